// Round 13
// baseline (761.086 us; speedup 1.0000x reference)
//
#include <hip/hip_runtime.h>
#include <hip/hip_bf16.h>
#include <math.h>

#define BB   4
#define NN   10000
#define NP   10112          // NN padded to multiple of 128
#define EE   160000         // = 1250 * 128
#define DD   128
#define OUTD 64
#define LL   4
#define NEGS 0.01f
#define MSTR 136            // s_mid/s_ho row stride (bf16 elems), 272B/row
#define RSF  34             // s_red row stride (fp32): 2-way max on read+write (~free)

typedef __attribute__((ext_vector_type(8))) short   short8;
typedef __attribute__((ext_vector_type(4))) float   floatx4;
typedef __attribute__((ext_vector_type(4))) uint    uintx4;

__device__ __forceinline__ float lrelu(float x) { return fmaxf(x, NEGS * x); }
__device__ __forceinline__ ushort f2bf(float x) {
    uint u = __builtin_bit_cast(uint, x);
    return (ushort)((u + 0x7FFFu + ((u >> 16) & 1u)) >> 16);
}
__device__ __forceinline__ float bf2f(ushort u) {
    uint v = ((uint)u) << 16;
    return __builtin_bit_cast(float, v);
}
__device__ __forceinline__ float bcf(uint u) { return __builtin_bit_cast(float, u); }

// ---- all weights -> MFMA B-fragment layout in ONE launch (192 blocks x 256)
__global__ void k_cvtw_all(const float* __restrict__ ew1, const float* __restrict__ ew2,
                           const float* __restrict__ nw1, const float* __restrict__ nw2,
                           ushort* __restrict__ wtopf, ushort* __restrict__ wmidf,
                           ushort* __restrict__ ew2f, ushort* __restrict__ nw1f,
                           ushort* __restrict__ nw2f) {
    int tid = blockIdx.x * 256 + threadIdx.x;
    const float* src; ushort* dst; int pitch, nks, loc;
    if (tid < 8192)       { src = ew1;                     dst = wtopf; pitch = 257; nks = 4; loc = tid; }
    else if (tid < 16384) { src = ew1 + (size_t)128 * DD;  dst = wmidf; pitch = 257; nks = 4; loc = tid - 8192; }
    else if (tid < 24576) { src = ew2;                     dst = ew2f;  pitch = 128; nks = 4; loc = tid - 16384; }
    else if (tid < 40960) { src = nw1;                     dst = nw1f;  pitch = 256; nks = 8; loc = tid - 24576; }
    else                  { src = nw2;                     dst = nw2f;  pitch = 128; nks = 4; loc = tid - 40960; }
    int lane = loc & 63;
    int nt   = (loc >> 6) & 7;
    int ks   = (loc >> 9) % nks;
    int l    = loc / (nks * 512);
    int quad = lane >> 4, l16 = lane & 15;
    int n = nt * 16 + l16;
    const float* s = src + (size_t)l * pitch * DD;
    ushort* d = dst + (size_t)loc * 8;
    #pragma unroll
    for (int j = 0; j < 8; ++j)
        d[j] = f2bf(s[(size_t)(ks * 32 + quad * 8 + j) * DD + n]);
}

// h0: bf16 only (no fp32 master)
__global__ void k_h0(const float* __restrict__ x, const float* __restrict__ w0,
                     const float* __restrict__ b0, ushort* __restrict__ hb) {
    int idx = blockIdx.x * 256 + threadIdx.x;
    if (idx >= BB * NP * DD) return;
    int d  = idx & (DD - 1);
    int bn = idx >> 7;
    int n  = bn % NP, b = bn / NP;
    float v = 0.0f;
    if (n < NN) {
        const float* p = x + ((size_t)b * NN + n) * 3;
        v = lrelu(b0[d] + p[0] * w0[d] + p[1] * w0[DD + d] + p[2] * w0[2 * DD + d]);
    }
    hb[idx] = f2bf(v);
}

__global__ void k_count(const int* __restrict__ col, float* __restrict__ cnt,
                        int* __restrict__ ecnt) {
    int e = blockIdx.x * blockDim.x + threadIdx.x;
    if (e < EE) {
        int c = col[e];
        atomicAdd(&cnt[c], 1.0f);
        atomicAdd(&ecnt[c], 1);
    }
}

__global__ __launch_bounds__(256) void k_scan(const int* __restrict__ ecnt,
                                              int* __restrict__ cursor) {
    __shared__ int s_sum[256];
    int t = threadIdx.x;
    int base = t * 40;
    int s = 0;
    for (int i = 0; i < 40; ++i) {
        int n = base + i;
        if (n < NN) s += ecnt[n];
    }
    s_sum[t] = s;
    __syncthreads();
    if (t == 0) {
        int a = 0;
        for (int i = 0; i < 256; ++i) { int v = s_sum[i]; s_sum[i] = a; a += v; }
    }
    __syncthreads();
    int a = s_sum[t];
    for (int i = 0; i < 40; ++i) {
        int n = base + i;
        if (n < NN) { cursor[n] = a; a += ecnt[n]; }
    }
}

__global__ void k_place(const int* __restrict__ row, const int* __restrict__ col,
                        int* __restrict__ cursor,
                        int* __restrict__ rowS, int* __restrict__ colS) {
    int e = blockIdx.x * blockDim.x + threadIdx.x;
    if (e >= EE) return;
    int c = col[e];
    int p = atomicAdd(&cursor[c], 1);
    rowS[p] = row[e];
    colS[p] = c;
}

// ---------------- initial P/Q (layer 0), 64-node blocks ----------------
__global__ __launch_bounds__(256) void k_pq(
    const ushort* __restrict__ hb, const ushort* __restrict__ wtf,
    const ushort* __restrict__ wmf, const float* __restrict__ b1,
    ushort* __restrict__ P, ushort* __restrict__ Q)
{
    __shared__ __align__(16) ushort s_out[64 * MSTR];
    const int g = blockIdx.x;
    const int b = (g & 7) >> 1;
    const int n0 = ((g >> 3) * 2 + (g & 1)) * 64;
    const int t = threadIdx.x;
    const int w = t >> 6, lane = t & 63, quad = lane >> 4, l16 = lane & 15;
    const int rw = w * 16;
    const int nw = n0 + rw;

    const ushort* hptr = hb + ((size_t)b * NP + nw + l16) * DD;
    float b1r[8];
    #pragma unroll
    for (int nt = 0; nt < 8; ++nt) b1r[nt] = b1[nt * 16 + l16];

    const short8* wt = (const short8*)wtf;
    const short8* wm = (const short8*)wmf;

    #pragma unroll
    for (int pass = 0; pass < 2; ++pass) {
        floatx4 ap[8];
        #pragma unroll
        for (int nt = 0; nt < 8; ++nt)
            #pragma unroll
            for (int r = 0; r < 4; ++r) ap[nt][r] = pass ? b1r[nt] : 0.0f;
        const short8* wv = pass ? wm : wt;
        #pragma unroll
        for (int ks = 0; ks < 4; ++ks) {
            short8 bf[8];
            #pragma unroll
            for (int nt = 0; nt < 8; ++nt) bf[nt] = wv[(ks * 8 + nt) * 64 + lane];
            short8 af = *(const short8*)(hptr + ks * 32 + quad * 8);
            #pragma unroll
            for (int nt = 0; nt < 8; ++nt)
                ap[nt] = __builtin_amdgcn_mfma_f32_16x16x32_bf16(af, bf[nt], ap[nt], 0, 0, 0);
        }
        #pragma unroll
        for (int nt = 0; nt < 8; ++nt)
            #pragma unroll
            for (int r = 0; r < 4; ++r)
                s_out[(rw + quad * 4 + r) * MSTR + nt * 16 + l16] = f2bf(ap[nt][r]);
        ushort* dst = pass ? Q : P;
        #pragma unroll
        for (int i = 0; i < 4; ++i) {
            int row = rw + i * 4 + quad;
            short8 v = *(const short8*)&s_out[row * MSTR + l16 * 8];
            *(short8*)(dst + ((size_t)b * NP + n0 + row) * DD + l16 * 8) = v;
        }
    }
}

// ---------------- NEW R13: edge phase-split ----------------
// Root cause of k_edge's pinned 3 waves/SIMD: gather dests (64 VGPR) + acc (32 AGPR)
// coexist in one body. Split: k_gath owns ONLY the random gathers+mid (low-reg, ~8
// blocks/CU = 2.7x TLP on the latency-critical reads; coalesced mid write), k_gemm
// reads mid COALESCED (streaming) and keeps GEMM+segreduce with no gather regs.
// Cost: 41MB/layer/batch mid roundtrip. ws_size-guarded; falls back to fused k_edge.

// k_gath: 8 threads/edge, 16 dims each; 32 edges/block; grid (EE/32)*BB
__global__ __launch_bounds__(256) void k_gath(
    const float* __restrict__ pos,
    const ushort* __restrict__ P, const ushort* __restrict__ Q,
    const int* __restrict__ rowS, const int* __restrict__ colS,
    const float* __restrict__ w1last,
    ushort* __restrict__ mid)
{
    const int g    = blockIdx.x;
    const int b    = g & 3;
    const int e    = (g >> 2) * 32 + (threadIdx.x >> 3);
    const int part = threadIdx.x & 7;
    const int d0   = part * 16;

    const int row = rowS[e], col = colS[e];
    const float* pr = pos + ((size_t)b * NN + row) * 3;
    const float* pc = pos + ((size_t)b * NN + col) * 3;
    float dx = pr[0] - pc[0], dy = pr[1] - pc[1], dz = pr[2] - pc[2];
    float ds = dx * dx + dy * dy + dz * dz;

    const ushort* pp = P + ((size_t)b * NP + row) * DD + d0;
    const ushort* qp = Q + ((size_t)b * NP + col) * DD + d0;
    uintx4 pf0 = *(const uintx4*)(pp);
    uintx4 pf1 = *(const uintx4*)(pp + 8);
    uintx4 qf0 = *(const uintx4*)(qp);
    uintx4 qf1 = *(const uintx4*)(qp + 8);

    uintx4 out[2];
    #pragma unroll
    for (int h = 0; h < 2; ++h) {
        uintx4 pv4 = h ? pf1 : pf0;
        uintx4 qv4 = h ? qf1 : qf0;
        floatx4 wl0 = *(const floatx4*)(w1last + d0 + h * 8);
        floatx4 wl1 = *(const floatx4*)(w1last + d0 + h * 8 + 4);
        float wl[8] = {wl0[0], wl0[1], wl0[2], wl0[3], wl1[0], wl1[1], wl1[2], wl1[3]};
        #pragma unroll
        for (int i = 0; i < 4; ++i) {
            uint pv = pv4[i], qv = qv4[i];
            float vlo = lrelu(bcf(pv << 16) + bcf(qv << 16) + ds * wl[2 * i]);
            float vhi = lrelu(bcf(pv & 0xFFFF0000u) + bcf(qv & 0xFFFF0000u) + ds * wl[2 * i + 1]);
            out[h][i] = __builtin_amdgcn_perm(
                __builtin_bit_cast(uint, vhi), __builtin_bit_cast(uint, vlo), 0x07060302u);
        }
    }
    ushort* mp = mid + ((size_t)b * EE + e) * DD + d0;
    *(uintx4*)(mp)     = out[0];
    *(uintx4*)(mp + 8) = out[1];
}

// k_gemm: GEMM + fp32 seg-reduce; A-fragments streamed coalesced from mid
__global__ __launch_bounds__(256, 4) void k_gemm(
    const int* __restrict__ colS,
    const ushort* __restrict__ mid,
    const ushort* __restrict__ w2f, const float* __restrict__ b2,
    float* __restrict__ aggr)
{
    __shared__ __align__(16) int    s_col[128];
    __shared__ __align__(16) float  s_red[128 * RSF];

    const int g    = blockIdx.x;
    const int b    = (g & 7) >> 1;
    const int tile = (g >> 3) * 2 + (g & 1);
    const int e0   = tile * 128;
    const int t    = threadIdx.x;
    const int w    = t >> 6, lane = t & 63;
    const int quad = lane >> 4, l16 = lane & 15;
    const int ew   = w * 32;

    if (t < 128) s_col[t] = colS[e0 + t];
    __syncthreads();

    const int rh    = lane >> 5;
    const int colL  = lane & 31;
    const int rbase = ew + rh * 16;
    int bmask = 0, cid0;
    {
        int prev = s_col[rbase];
        cid0 = prev;
        #pragma unroll
        for (int r2 = 1; r2 < 16; ++r2) {
            int c = s_col[rbase + r2];
            if (c != prev) bmask |= (1 << r2);
            prev = c;
        }
    }

    const ushort* mrow[2];
    #pragma unroll
    for (int mt = 0; mt < 2; ++mt)
        mrow[mt] = mid + ((size_t)b * EE + e0 + ew + mt * 16 + l16) * DD + quad * 8;

    float* aggr_bd = aggr + (size_t)b * NP * DD;
    const short8* w2v = (const short8*)w2f;

    #pragma unroll
    for (int ph = 0; ph < 2; ++ph) {
        float b2r4[4];
        #pragma unroll
        for (int ntl = 0; ntl < 4; ++ntl) b2r4[ntl] = b2[(ph * 4 + ntl) * 16 + l16];

        floatx4 acc[2][4];
        #pragma unroll
        for (int mt = 0; mt < 2; ++mt)
            #pragma unroll
            for (int ntl = 0; ntl < 4; ++ntl)
                #pragma unroll
                for (int r = 0; r < 4; ++r) acc[mt][ntl][r] = b2r4[ntl];

        #pragma unroll
        for (int ks = 0; ks < 4; ++ks) {
            short8 bf[4];
            #pragma unroll
            for (int ntl = 0; ntl < 4; ++ntl)
                bf[ntl] = w2v[(ks * 8 + ph * 4 + ntl) * 64 + lane];
            #pragma unroll
            for (int mt = 0; mt < 2; ++mt) {
                short8 af = *(const short8*)(mrow[mt] + ks * 32);
                #pragma unroll
                for (int ntl = 0; ntl < 4; ++ntl)
                    acc[mt][ntl] = __builtin_amdgcn_mfma_f32_16x16x32_bf16(af, bf[ntl], acc[mt][ntl], 0, 0, 0);
            }
        }

        #pragma unroll
        for (int sp = 0; sp < 2; ++sp) {
            #pragma unroll
            for (int mt = 0; mt < 2; ++mt)
                #pragma unroll
                for (int j = 0; j < 2; ++j) {
                    const int ntl = sp * 2 + j;
                    #pragma unroll
                    for (int r = 0; r < 4; ++r)
                        s_red[(ew + mt * 16 + quad * 4 + r) * RSF + j * 16 + l16] =
                            lrelu(acc[mt][ntl][r]);
                }

            const int d = ph * 64 + sp * 32 + colL;
            float* ab = aggr_bd + d;
            float run = 0.0f;
            int cid = cid0;
            #pragma unroll
            for (int r = 0; r < 16; ++r) {
                float v = s_red[(rbase + r) * RSF + colL];
                if (bmask & (1 << r)) {
                    atomicAdd(ab + (size_t)cid * DD, run);
                    run = 0.0f;
                    cid = s_col[rbase + r];
                }
                run += v;
            }
            atomicAdd(ab + (size_t)cid * DD, run);
        }
    }
}

// ---------------- fused k_edge (R4/R9 proven 75us) -- fallback if ws too small ----------------
__global__ __launch_bounds__(256, 4) void k_edge_fused(
    const float* __restrict__ pos,
    const ushort* __restrict__ P, const ushort* __restrict__ Q,
    const int* __restrict__ rowS, const int* __restrict__ colS,
    const float* __restrict__ w1last,
    const ushort* __restrict__ w2f, const float* __restrict__ b2,
    float* __restrict__ aggr)
{
    __shared__ __align__(16) int    s_col[128];
    __shared__ __align__(16) float  s_ds[128];
    __shared__ __align__(16) float  s_red[128 * RSF];

    const int g    = blockIdx.x;
    const int b    = (g & 7) >> 1;
    const int tile = (g >> 3) * 2 + (g & 1);
    const int e0   = tile * 128;
    const int t    = threadIdx.x;
    const int w    = t >> 6, lane = t & 63;
    const int quad = lane >> 4, l16 = lane & 15;
    const int ew   = w * 32;

    const ushort* pp[2];
    const ushort* qp[2];
    #pragma unroll
    for (int mt = 0; mt < 2; ++mt) {
        int el = e0 + ew + mt * 16 + l16;
        pp[mt] = P + ((size_t)b * NP + rowS[el]) * DD;
        qp[mt] = Q + ((size_t)b * NP + colS[el]) * DD;
    }

    uintx4 pf[2][4], qf[2][4];
    #pragma unroll
    for (int ks = 0; ks < 4; ++ks) {
        const int koff = ks * 32 + quad * 8;
        #pragma unroll
        for (int mt = 0; mt < 2; ++mt) {
            pf[mt][ks] = *(const uintx4*)(pp[mt] + koff);
            qf[mt][ks] = *(const uintx4*)(qp[mt] + koff);
        }
    }

    if (t < 128) {
        int e = e0 + t;
        int r = rowS[e], c = colS[e];
        s_col[t] = c;
        const float* pr = pos + ((size_t)b * NN + r) * 3;
        const float* pc = pos + ((size_t)b * NN + c) * 3;
        float dx = pr[0] - pc[0], dy = pr[1] - pc[1], dz = pr[2] - pc[2];
        s_ds[t] = dx * dx + dy * dy + dz * dz;
    }
    __syncthreads();

    const int rh    = lane >> 5;
    const int colL  = lane & 31;
    const int rbase = ew + rh * 16;
    int bmask = 0, cid0;
    {
        int prev = s_col[rbase];
        cid0 = prev;
        #pragma unroll
        for (int r2 = 1; r2 < 16; ++r2) {
            int c = s_col[rbase + r2];
            if (c != prev) bmask |= (1 << r2);
            prev = c;
        }
    }

    float dsv[2];
    #pragma unroll
    for (int mt = 0; mt < 2; ++mt) dsv[mt] = s_ds[ew + mt * 16 + l16];

    uintx4 mid[2][4];
    #pragma unroll
    for (int ks = 0; ks < 4; ++ks) {
        const int koff = ks * 32 + quad * 8;
        floatx4 wl0 = *(const floatx4*)(w1last + koff);
        floatx4 wl1 = *(const floatx4*)(w1last + koff + 4);
        float wl[8] = {wl0[0], wl0[1], wl0[2], wl0[3], wl1[0], wl1[1], wl1[2], wl1[3]};
        #pragma unroll
        for (int mt = 0; mt < 2; ++mt) {
            #pragma unroll
            for (int i = 0; i < 4; ++i) {
                uint pv = pf[mt][ks][i], qv = qf[mt][ks][i];
                float vlo = lrelu(bcf(pv << 16) + bcf(qv << 16) + dsv[mt] * wl[2 * i]);
                float vhi = lrelu(bcf(pv & 0xFFFF0000u) + bcf(qv & 0xFFFF0000u) + dsv[mt] * wl[2 * i + 1]);
                mid[mt][ks][i] = __builtin_amdgcn_perm(
                    __builtin_bit_cast(uint, vhi), __builtin_bit_cast(uint, vlo), 0x07060302u);
            }
        }
    }

    float* aggr_bd = aggr + (size_t)b * NP * DD;
    const short8* w2v = (const short8*)w2f;
    #pragma unroll
    for (int ph = 0; ph < 2; ++ph) {
        float b2r4[4];
        #pragma unroll
        for (int ntl = 0; ntl < 4; ++ntl) b2r4[ntl] = b2[(ph * 4 + ntl) * 16 + l16];

        floatx4 acc[2][4];
        #pragma unroll
        for (int mt = 0; mt < 2; ++mt)
            #pragma unroll
            for (int ntl = 0; ntl < 4; ++ntl)
                #pragma unroll
                for (int r = 0; r < 4; ++r) acc[mt][ntl][r] = b2r4[ntl];

        #pragma unroll
        for (int ks = 0; ks < 4; ++ks) {
            short8 bf[4];
            #pragma unroll
            for (int ntl = 0; ntl < 4; ++ntl)
                bf[ntl] = w2v[(ks * 8 + ph * 4 + ntl) * 64 + lane];
            #pragma unroll
            for (int mt = 0; mt < 2; ++mt) {
                short8 af = __builtin_bit_cast(short8, mid[mt][ks]);
                #pragma unroll
                for (int ntl = 0; ntl < 4; ++ntl)
                    acc[mt][ntl] = __builtin_amdgcn_mfma_f32_16x16x32_bf16(af, bf[ntl], acc[mt][ntl], 0, 0, 0);
            }
        }

        #pragma unroll
        for (int sp = 0; sp < 2; ++sp) {
            #pragma unroll
            for (int mt = 0; mt < 2; ++mt)
                #pragma unroll
                for (int j = 0; j < 2; ++j) {
                    const int ntl = sp * 2 + j;
                    #pragma unroll
                    for (int r = 0; r < 4; ++r)
                        s_red[(ew + mt * 16 + quad * 4 + r) * RSF + j * 16 + l16] =
                            lrelu(acc[mt][ntl][r]);
                }

            const int d = ph * 64 + sp * 32 + colL;
            float* ab = aggr_bd + d;
            float run = 0.0f;
            int cid = cid0;
            #pragma unroll
            for (int r = 0; r < 16; ++r) {
                float v = s_red[(rbase + r) * RSF + colL];
                if (bmask & (1 << r)) {
                    atomicAdd(ab + (size_t)cid * DD, run);
                    run = 0.0f;
                    cid = s_col[rbase + r];
                }
                run += v;
            }
            atomicAdd(ab + (size_t)cid * DD, run);
        }
    }
}

// ---------------- node MLP: column-split GEMM2/PQ (R12, best) ----------------
__global__ __launch_bounds__(256) void k_node(
    ushort* hb, float* aggr, const float* __restrict__ cnt,
    const float* __restrict__ cw, const float* __restrict__ cb,
    const ushort* __restrict__ w1f, const float* __restrict__ b1,
    const ushort* __restrict__ w2f, const float* __restrict__ b2,
    float* __restrict__ pos,
    int do_pq,
    const ushort* __restrict__ wtn, const ushort* __restrict__ wmn,
    const float* __restrict__ b1n,
    ushort* __restrict__ P, ushort* __restrict__ Q)
{
    __shared__ __align__(16) ushort s_mid[64 * MSTR];
    __shared__ __align__(16) ushort s_ho[64 * MSTR];

    const int g    = blockIdx.x;
    const int b    = (g & 7) >> 1;
    const int n0   = ((g >> 3) * 2 + (g & 1)) * 64;
    const int t    = threadIdx.x;
    const int w    = t >> 6, lane = t & 63;
    const int quad = lane >> 4, l16 = lane & 15;
    const int rw   = w * 16;
    const int nw   = n0 + rw;
    const int w2i  = w * 2;

    #pragma unroll
    for (int i = 0; i < 4; ++i) {
        int row = rw + i * 4 + quad;
        short8 v = *(const short8*)(hb + ((size_t)b * NP + n0 + row) * DD + l16 * 8);
        *(short8*)&s_ho[row * MSTR + l16 * 8] = v;
    }

    float* aptr = aggr + ((size_t)b * NP + nw + l16) * DD;
    float inv = 0.0f;
    {
        int node = nw + l16;
        if (node < NN) { float dn = cnt[node]; inv = 1.0f / fmaxf(dn, 1.0f); }
    }
    float b1r[8];
    #pragma unroll
    for (int nt = 0; nt < 8; ++nt) b1r[nt] = b1[nt * 16 + l16];
    float b2r2[2];
    #pragma unroll
    for (int nt = 0; nt < 2; ++nt) b2r2[nt] = b2[(w2i + nt) * 16 + l16];

    floatx4 acc[8];
    #pragma unroll
    for (int nt = 0; nt < 8; ++nt)
        #pragma unroll
        for (int r = 0; r < 4; ++r) acc[nt][r] = b1r[nt];

    float cwacc = 0.0f;
    const floatx4 zero4 = {0.0f, 0.0f, 0.0f, 0.0f};
    const short8* w1v = (const short8*)w1f;
    #pragma unroll
    for (int ks = 0; ks < 8; ++ks) {
        short8 bf[8];
        #pragma unroll
        for (int nt = 0; nt < 8; ++nt) bf[nt] = w1v[(ks * 8 + nt) * 64 + lane];
        const int koff = (ks & 3) * 32 + quad * 8;
        if (ks < 4) {
            short8 af = *(const short8*)(&s_ho[(rw + l16) * MSTR + koff]);
            #pragma unroll
            for (int nt = 0; nt < 8; ++nt)
                acc[nt] = __builtin_amdgcn_mfma_f32_16x16x32_bf16(af, bf[nt], acc[nt], 0, 0, 0);
        } else {
            floatx4 cw0 = *(const floatx4*)(cw + koff);
            floatx4 cw1 = *(const floatx4*)(cw + koff + 4);
            floatx4 a0 = *(const floatx4*)(aptr + koff);
            floatx4 a1 = *(const floatx4*)(aptr + koff + 4);
            *(floatx4*)(aptr + koff)     = zero4;
            *(floatx4*)(aptr + koff + 4) = zero4;
            short8 af;
            #pragma unroll
            for (int j = 0; j < 4; ++j) {
                float v = a0[j] * inv;
                af[j] = (short)f2bf(v);
                cwacc += v * cw0[j];
            }
            #pragma unroll
            for (int j = 0; j < 4; ++j) {
                float v = a1[j] * inv;
                af[4 + j] = (short)f2bf(v);
                cwacc += v * cw1[j];
            }
            #pragma unroll
            for (int nt = 0; nt < 8; ++nt)
                acc[nt] = __builtin_amdgcn_mfma_f32_16x16x32_bf16(af, bf[nt], acc[nt], 0, 0, 0);
        }
    }

    {
        float full = cwacc;
        full += __shfl_xor(full, 16);
        full += __shfl_xor(full, 32);
        int node = nw + l16;
        if (quad == 0 && node < NN) {
            float cu = 0.1f * tanhf(full + cb[0]);
            float* pp = pos + ((size_t)b * NN + node) * 3;
            pp[0] += cu; pp[1] += cu; pp[2] += cu;
        }
    }

    #pragma unroll
    for (int nt = 0; nt < 8; ++nt)
        #pragma unroll
        for (int r = 0; r < 4; ++r)
            s_mid[(rw + quad * 4 + r) * MSTR + nt * 16 + l16] = f2bf(lrelu(acc[nt][r]));

    __syncthreads();

    floatx4 acc2[4][2];
    #pragma unroll
    for (int rt = 0; rt < 4; ++rt)
        #pragma unroll
        for (int nt = 0; nt < 2; ++nt)
            #pragma unroll
            for (int r = 0; r < 4; ++r) acc2[rt][nt][r] = b2r2[nt];

    const short8* w2v = (const short8*)w2f;
    #pragma unroll
    for (int ks = 0; ks < 4; ++ks) {
        short8 bfc[2];
        #pragma unroll
        for (int nt = 0; nt < 2; ++nt)
            bfc[nt] = w2v[(ks * 8 + w2i + nt) * 64 + lane];
        #pragma unroll
        for (int rt = 0; rt < 4; ++rt) {
            short8 af = *(const short8*)(&s_mid[(rt * 16 + l16) * MSTR + ks * 32 + quad * 8]);
            #pragma unroll
            for (int nt = 0; nt < 2; ++nt)
                acc2[rt][nt] = __builtin_amdgcn_mfma_f32_16x16x32_bf16(af, bfc[nt], acc2[rt][nt], 0, 0, 0);
        }
    }

    __syncthreads();

    #pragma unroll
    for (int rt = 0; rt < 4; ++rt)
        #pragma unroll
        for (int nt = 0; nt < 2; ++nt)
            #pragma unroll
            for (int r = 0; r < 4; ++r) {
                int row = rt * 16 + quad * 4 + r;
                int col = w2i * 16 + nt * 16 + l16;
                float hold = bf2f(s_ho[row * MSTR + col]);
                s_mid[row * MSTR + col] = f2bf(hold + lrelu(acc2[rt][nt][r]));
            }

    __syncthreads();

    #pragma unroll
    for (int i = 0; i < 4; ++i) {
        int row = rw + i * 4 + quad;
        int n = n0 + row;
        short8 v = *(const short8*)&s_mid[row * MSTR + l16 * 8];
        if (n < NN)
            *(short8*)(hb + ((size_t)b * NP + n) * DD + l16 * 8) = v;
    }

    if (do_pq) {
        const short8* wt = (const short8*)wtn;
        const short8* wm = (const short8*)wmn;
        float b1nr2[2];
        #pragma unroll
        for (int nt = 0; nt < 2; ++nt) b1nr2[nt] = b1n[(w2i + nt) * 16 + l16];

        #pragma unroll
        for (int pass = 0; pass < 2; ++pass) {
            floatx4 ap[4][2];
            #pragma unroll
            for (int rt = 0; rt < 4; ++rt)
                #pragma unroll
                for (int nt = 0; nt < 2; ++nt)
                    #pragma unroll
                    for (int r = 0; r < 4; ++r) ap[rt][nt][r] = pass ? b1nr2[nt] : 0.0f;
            const short8* wv = pass ? wm : wt;
            #pragma unroll
            for (int ks = 0; ks < 4; ++ks) {
                short8 bfp[2];
                #pragma unroll
                for (int nt = 0; nt < 2; ++nt)
                    bfp[nt] = wv[(ks * 8 + w2i + nt) * 64 + lane];
                #pragma unroll
                for (int rt = 0; rt < 4; ++rt) {
                    short8 af = *(const short8*)(&s_mid[(rt * 16 + l16) * MSTR + ks * 32 + quad * 8]);
                    #pragma unroll
                    for (int nt = 0; nt < 2; ++nt)
                        ap[rt][nt] = __builtin_amdgcn_mfma_f32_16x16x32_bf16(af, bfp[nt], ap[rt][nt], 0, 0, 0);
                }
            }
            if (pass) __syncthreads();
            #pragma unroll
            for (int rt = 0; rt < 4; ++rt)
                #pragma unroll
                for (int nt = 0; nt < 2; ++nt)
                    #pragma unroll
                    for (int r = 0; r < 4; ++r)
                        s_ho[(rt * 16 + quad * 4 + r) * MSTR + w2i * 16 + nt * 16 + l16] =
                            f2bf(ap[rt][nt][r]);
            __syncthreads();
            ushort* dst = pass ? Q : P;
            #pragma unroll
            for (int i = 0; i < 4; ++i) {
                int row = rw + i * 4 + quad;
                short8 v = *(const short8*)&s_ho[row * MSTR + l16 * 8];
                *(short8*)(dst + ((size_t)b * NP + n0 + row) * DD + l16 * 8) = v;
            }
        }
    }
}

#define NPC 50
__global__ void k_mean(const ushort* __restrict__ hb, float* __restrict__ hm) {
    int b  = blockIdx.y;
    int n0 = blockIdx.x * NPC;
    int d  = threadIdx.x;
    float s = 0.0f;
    for (int n = n0; n < n0 + NPC; ++n) s += bf2f(hb[((size_t)b * NP + n) * DD + d]);
    atomicAdd(&hm[b * DD + d], s);
}

__global__ void k_proj(const float* __restrict__ hm, const float* __restrict__ wp,
                       const float* __restrict__ bp, float* __restrict__ out) {
    int t = threadIdx.x;
    int b = t >> 6, o = t & (OUTD - 1);
    float s = 0.0f;
    for (int d2 = 0; d2 < DD; ++d2) s += hm[b * DD + d2] * wp[d2 * OUTD + o];
    s = s * (1.0f / NN) + bp[o];
    out[b * OUTD + o] = lrelu(s);
}

extern "C" void kernel_launch(void* const* d_in, const int* in_sizes, int n_in,
                              void* d_out, int out_size, void* d_ws, size_t ws_size,
                              hipStream_t stream) {
    (void)in_sizes; (void)n_in; (void)out_size;
    const float* x   = (const float*)d_in[0];
    const int*   ei  = (const int*)d_in[1];
    const float* w0  = (const float*)d_in[2];
    const float* b0  = (const float*)d_in[3];
    const float* ew1 = (const float*)d_in[4];
    const float* eb1 = (const float*)d_in[5];
    const float* ew2 = (const float*)d_in[6];
    const float* eb2 = (const float*)d_in[7];
    const float* cw  = (const float*)d_in[8];
    const float* cb  = (const float*)d_in[9];
    const float* nw1 = (const float*)d_in[10];
    const float* nb1 = (const float*)d_in[11];
    const float* nw2 = (const float*)d_in[12];
    const float* nb2 = (const float*)d_in[13];
    const float* wp  = (const float*)d_in[14];
    const float* bp  = (const float*)d_in[15];
    const int* row = ei;
    const int* col = ei + EE;

    const size_t HSZ = (size_t)BB * NP * DD;
    float* ws   = (float*)d_ws;
    float* aggr = ws;
    float* pos  = aggr + HSZ;
    float* cnt  = pos + (size_t)BB * NN * 3;
    float* hm   = cnt + NN;
    ushort* hb    = (ushort*)(hm + 512);
    ushort* Pb    = hb + HSZ;
    ushort* Qb    = Pb + HSZ;
    ushort* wtopf = Qb + HSZ;                           // LL*16384
    ushort* wmidf = wtopf + (size_t)LL * 16384;
    ushort* ew2f  = wmidf + (size_t)LL * 16384;
    ushort* nw1f  = ew2f + (size_t)LL * 16384;          // LL*32768
    ushort* nw2f  = nw1f + (size_t)LL * 32768;
    int* ecnt   = (int*)(nw2f + (size_t)LL * 16384);
    int* cursor = ecnt + NN;
    int* rowS   = cursor + NN;
    int* colS   = rowS + EE;
    ushort* midb = (ushort*)(colS + EE);                // BB*EE*DD bf16 (164MB)

    const size_t need = (size_t)((char*)(midb + (size_t)BB * EE * DD) - (char*)d_ws);
    const bool use_split = (ws_size >= need);

    hipMemcpyAsync(pos, x, sizeof(float) * (size_t)BB * NN * 3,
                   hipMemcpyDeviceToDevice, stream);
    hipMemsetAsync(cnt, 0, sizeof(float) * NN, stream);
    hipMemsetAsync(ecnt, 0, sizeof(int) * NN, stream);
    hipMemsetAsync(hm, 0, sizeof(float) * BB * DD, stream);
    hipMemsetAsync(aggr, 0, sizeof(float) * HSZ, stream);   // layers 1..3 self-cleaned by k_node

    k_cvtw_all<<<192, 256, 0, stream>>>(ew1, ew2, nw1, nw2,
                                        wtopf, wmidf, ew2f, nw1f, nw2f);

    k_h0<<<((int)HSZ + 255) / 256, 256, 0, stream>>>(x, w0, b0, hb);
    k_count<<<(EE + 255) / 256, 256, 0, stream>>>(col, cnt, ecnt);
    k_scan<<<1, 256, 0, stream>>>(ecnt, cursor);
    k_place<<<(EE + 255) / 256, 256, 0, stream>>>(row, col, cursor, rowS, colS);

    k_pq<<<(NP / 64) * BB, 256, 0, stream>>>(hb, wtopf, wmidf, eb1, Pb, Qb);

    for (int i = 0; i < LL; ++i) {
        const float* w1l = ew1 + (size_t)i * 257 * DD + (size_t)256 * DD;
        if (use_split) {
            k_gath<<<(EE / 32) * BB, 256, 0, stream>>>(
                pos, Pb, Qb, rowS, colS, w1l, midb);
            k_gemm<<<(EE / 128) * BB, 256, 0, stream>>>(
                colS, midb, ew2f + (size_t)i * 16384, eb2 + (size_t)i * DD, aggr);
        } else {
            k_edge_fused<<<(EE / 128) * BB, 256, 0, stream>>>(
                pos, Pb, Qb, rowS, colS, w1l,
                ew2f + (size_t)i * 16384, eb2 + (size_t)i * DD, aggr);
        }
        int nx = (i < LL - 1) ? (i + 1) : i;
        k_node<<<(NP / 64) * BB, 256, 0, stream>>>(
            hb, aggr, cnt,
            cw + (size_t)i * DD, cb + i,
            nw1f + (size_t)i * 32768, nb1 + (size_t)i * DD,
            nw2f + (size_t)i * 16384, nb2 + (size_t)i * DD,
            pos,
            (i < LL - 1) ? 1 : 0,
            wtopf + (size_t)nx * 16384, wmidf + (size_t)nx * 16384,
            eb1 + (size_t)nx * DD,
            Pb, Qb);
    }

    k_mean<<<dim3(NN / NPC, BB), DD, 0, stream>>>(hb, hm);
    k_proj<<<1, 256, 0, stream>>>(hm, wp, bp, (float*)d_out);
}

// Round 14
// 562.061 us; speedup vs baseline: 1.3541x; 1.3541x over previous
//
#include <hip/hip_runtime.h>
#include <hip/hip_bf16.h>
#include <math.h>

#define BB   4
#define NN   10000
#define NP   10112          // NN padded to multiple of 128
#define EE   160000         // = 1250 * 128
#define DD   128
#define OUTD 64
#define LL   4
#define NEGS 0.01f
#define MSTR 136            // s_mid/s_ho row stride (bf16 elems), 272B/row
#define RSF  34             // s_red row stride (fp32): 2-way max on read+write (~free)

typedef __attribute__((ext_vector_type(8))) short   short8;
typedef __attribute__((ext_vector_type(4))) float   floatx4;
typedef __attribute__((ext_vector_type(4))) uint    uintx4;

__device__ __forceinline__ float lrelu(float x) { return fmaxf(x, NEGS * x); }
__device__ __forceinline__ ushort f2bf(float x) {
    uint u = __builtin_bit_cast(uint, x);
    return (ushort)((u + 0x7FFFu + ((u >> 16) & 1u)) >> 16);
}
__device__ __forceinline__ float bf2f(ushort u) {
    uint v = ((uint)u) << 16;
    return __builtin_bit_cast(float, v);
}
__device__ __forceinline__ float bcf(uint u) { return __builtin_bit_cast(float, u); }

// ---- all weights -> MFMA B-fragment layout in ONE launch (192 blocks x 256)
__global__ void k_cvtw_all(const float* __restrict__ ew1, const float* __restrict__ ew2,
                           const float* __restrict__ nw1, const float* __restrict__ nw2,
                           ushort* __restrict__ wtopf, ushort* __restrict__ wmidf,
                           ushort* __restrict__ ew2f, ushort* __restrict__ nw1f,
                           ushort* __restrict__ nw2f) {
    int tid = blockIdx.x * 256 + threadIdx.x;
    const float* src; ushort* dst; int pitch, nks, loc;
    if (tid < 8192)       { src = ew1;                     dst = wtopf; pitch = 257; nks = 4; loc = tid; }
    else if (tid < 16384) { src = ew1 + (size_t)128 * DD;  dst = wmidf; pitch = 257; nks = 4; loc = tid - 8192; }
    else if (tid < 24576) { src = ew2;                     dst = ew2f;  pitch = 128; nks = 4; loc = tid - 16384; }
    else if (tid < 40960) { src = nw1;                     dst = nw1f;  pitch = 256; nks = 8; loc = tid - 24576; }
    else                  { src = nw2;                     dst = nw2f;  pitch = 128; nks = 4; loc = tid - 40960; }
    int lane = loc & 63;
    int nt   = (loc >> 6) & 7;
    int ks   = (loc >> 9) % nks;
    int l    = loc / (nks * 512);
    int quad = lane >> 4, l16 = lane & 15;
    int n = nt * 16 + l16;
    const float* s = src + (size_t)l * pitch * DD;
    ushort* d = dst + (size_t)loc * 8;
    #pragma unroll
    for (int j = 0; j < 8; ++j)
        d[j] = f2bf(s[(size_t)(ks * 32 + quad * 8 + j) * DD + n]);
}

// h0: bf16 only (no fp32 master)
__global__ void k_h0(const float* __restrict__ x, const float* __restrict__ w0,
                     const float* __restrict__ b0, ushort* __restrict__ hb) {
    int idx = blockIdx.x * 256 + threadIdx.x;
    if (idx >= BB * NP * DD) return;
    int d  = idx & (DD - 1);
    int bn = idx >> 7;
    int n  = bn % NP, b = bn / NP;
    float v = 0.0f;
    if (n < NN) {
        const float* p = x + ((size_t)b * NN + n) * 3;
        v = lrelu(b0[d] + p[0] * w0[d] + p[1] * w0[DD + d] + p[2] * w0[2 * DD + d]);
    }
    hb[idx] = f2bf(v);
}

__global__ void k_count(const int* __restrict__ col, float* __restrict__ cnt,
                        int* __restrict__ ecnt) {
    int e = blockIdx.x * blockDim.x + threadIdx.x;
    if (e < EE) {
        int c = col[e];
        atomicAdd(&cnt[c], 1.0f);
        atomicAdd(&ecnt[c], 1);
    }
}

__global__ __launch_bounds__(256) void k_scan(const int* __restrict__ ecnt,
                                              int* __restrict__ cursor) {
    __shared__ int s_sum[256];
    int t = threadIdx.x;
    int base = t * 40;
    int s = 0;
    for (int i = 0; i < 40; ++i) {
        int n = base + i;
        if (n < NN) s += ecnt[n];
    }
    s_sum[t] = s;
    __syncthreads();
    if (t == 0) {
        int a = 0;
        for (int i = 0; i < 256; ++i) { int v = s_sum[i]; s_sum[i] = a; a += v; }
    }
    __syncthreads();
    int a = s_sum[t];
    for (int i = 0; i < 40; ++i) {
        int n = base + i;
        if (n < NN) { cursor[n] = a; a += ecnt[n]; }
    }
}

__global__ void k_place(const int* __restrict__ row, const int* __restrict__ col,
                        int* __restrict__ cursor,
                        int* __restrict__ rowS, int* __restrict__ colS) {
    int e = blockIdx.x * blockDim.x + threadIdx.x;
    if (e >= EE) return;
    int c = col[e];
    int p = atomicAdd(&cursor[c], 1);
    rowS[p] = row[e];
    colS[p] = c;
}

// ---------------- initial P/Q (layer 0), 64-node blocks ----------------
__global__ __launch_bounds__(256) void k_pq(
    const ushort* __restrict__ hb, const ushort* __restrict__ wtf,
    const ushort* __restrict__ wmf, const float* __restrict__ b1,
    ushort* __restrict__ P, ushort* __restrict__ Q)
{
    __shared__ __align__(16) ushort s_out[64 * MSTR];
    const int g = blockIdx.x;
    const int b = (g & 7) >> 1;
    const int n0 = ((g >> 3) * 2 + (g & 1)) * 64;
    const int t = threadIdx.x;
    const int w = t >> 6, lane = t & 63, quad = lane >> 4, l16 = lane & 15;
    const int rw = w * 16;
    const int nw = n0 + rw;

    const ushort* hptr = hb + ((size_t)b * NP + nw + l16) * DD;
    float b1r[8];
    #pragma unroll
    for (int nt = 0; nt < 8; ++nt) b1r[nt] = b1[nt * 16 + l16];

    const short8* wt = (const short8*)wtf;
    const short8* wm = (const short8*)wmf;

    #pragma unroll
    for (int pass = 0; pass < 2; ++pass) {
        floatx4 ap[8];
        #pragma unroll
        for (int nt = 0; nt < 8; ++nt)
            #pragma unroll
            for (int r = 0; r < 4; ++r) ap[nt][r] = pass ? b1r[nt] : 0.0f;
        const short8* wv = pass ? wm : wt;
        #pragma unroll
        for (int ks = 0; ks < 4; ++ks) {
            short8 bf[8];
            #pragma unroll
            for (int nt = 0; nt < 8; ++nt) bf[nt] = wv[(ks * 8 + nt) * 64 + lane];
            short8 af = *(const short8*)(hptr + ks * 32 + quad * 8);
            #pragma unroll
            for (int nt = 0; nt < 8; ++nt)
                ap[nt] = __builtin_amdgcn_mfma_f32_16x16x32_bf16(af, bf[nt], ap[nt], 0, 0, 0);
        }
        #pragma unroll
        for (int nt = 0; nt < 8; ++nt)
            #pragma unroll
            for (int r = 0; r < 4; ++r)
                s_out[(rw + quad * 4 + r) * MSTR + nt * 16 + l16] = f2bf(ap[nt][r]);
        ushort* dst = pass ? Q : P;
        #pragma unroll
        for (int i = 0; i < 4; ++i) {
            int row = rw + i * 4 + quad;
            short8 v = *(const short8*)&s_out[row * MSTR + l16 * 8];
            *(short8*)(dst + ((size_t)b * NP + n0 + row) * DD + l16 * 8) = v;
        }
    }
}

// ---------------- edge kernel: R4/R9 fused body (structural floor ~75us) ----------------
// 8 falsified theories incl. R13 phase-split (k_gemm alone = 72us proves back-end is
// the floor; gathers fully hidden). Accepted.
__global__ __launch_bounds__(256, 4) void k_edge(
    const float* __restrict__ pos,
    const ushort* __restrict__ P, const ushort* __restrict__ Q,
    const int* __restrict__ rowS, const int* __restrict__ colS,
    const float* __restrict__ w1last,
    const ushort* __restrict__ w2f, const float* __restrict__ b2,
    float* __restrict__ aggr)
{
    __shared__ __align__(16) int    s_col[128];
    __shared__ __align__(16) float  s_ds[128];
    __shared__ __align__(16) float  s_red[128 * RSF];

    const int g    = blockIdx.x;
    const int b    = (g & 7) >> 1;
    const int tile = (g >> 3) * 2 + (g & 1);
    const int e0   = tile * 128;
    const int t    = threadIdx.x;
    const int w    = t >> 6, lane = t & 63;
    const int quad = lane >> 4, l16 = lane & 15;
    const int ew   = w * 32;

    const ushort* pp[2];
    const ushort* qp[2];
    #pragma unroll
    for (int mt = 0; mt < 2; ++mt) {
        int el = e0 + ew + mt * 16 + l16;
        pp[mt] = P + ((size_t)b * NP + rowS[el]) * DD;
        qp[mt] = Q + ((size_t)b * NP + colS[el]) * DD;
    }

    uintx4 pf[2][4], qf[2][4];
    #pragma unroll
    for (int ks = 0; ks < 4; ++ks) {
        const int koff = ks * 32 + quad * 8;
        #pragma unroll
        for (int mt = 0; mt < 2; ++mt) {
            pf[mt][ks] = *(const uintx4*)(pp[mt] + koff);
            qf[mt][ks] = *(const uintx4*)(qp[mt] + koff);
        }
    }

    if (t < 128) {
        int e = e0 + t;
        int r = rowS[e], c = colS[e];
        s_col[t] = c;
        const float* pr = pos + ((size_t)b * NN + r) * 3;
        const float* pc = pos + ((size_t)b * NN + c) * 3;
        float dx = pr[0] - pc[0], dy = pr[1] - pc[1], dz = pr[2] - pc[2];
        s_ds[t] = dx * dx + dy * dy + dz * dz;
    }
    __syncthreads();

    const int rh    = lane >> 5;
    const int colL  = lane & 31;
    const int rbase = ew + rh * 16;
    int bmask = 0, cid0;
    {
        int prev = s_col[rbase];
        cid0 = prev;
        #pragma unroll
        for (int r2 = 1; r2 < 16; ++r2) {
            int c = s_col[rbase + r2];
            if (c != prev) bmask |= (1 << r2);
            prev = c;
        }
    }

    float dsv[2];
    #pragma unroll
    for (int mt = 0; mt < 2; ++mt) dsv[mt] = s_ds[ew + mt * 16 + l16];

    uintx4 mid[2][4];
    #pragma unroll
    for (int ks = 0; ks < 4; ++ks) {
        const int koff = ks * 32 + quad * 8;
        floatx4 wl0 = *(const floatx4*)(w1last + koff);
        floatx4 wl1 = *(const floatx4*)(w1last + koff + 4);
        float wl[8] = {wl0[0], wl0[1], wl0[2], wl0[3], wl1[0], wl1[1], wl1[2], wl1[3]};
        #pragma unroll
        for (int mt = 0; mt < 2; ++mt) {
            #pragma unroll
            for (int i = 0; i < 4; ++i) {
                uint pv = pf[mt][ks][i], qv = qf[mt][ks][i];
                float vlo = lrelu(bcf(pv << 16) + bcf(qv << 16) + dsv[mt] * wl[2 * i]);
                float vhi = lrelu(bcf(pv & 0xFFFF0000u) + bcf(qv & 0xFFFF0000u) + dsv[mt] * wl[2 * i + 1]);
                mid[mt][ks][i] = __builtin_amdgcn_perm(
                    __builtin_bit_cast(uint, vhi), __builtin_bit_cast(uint, vlo), 0x07060302u);
            }
        }
    }

    float* aggr_bd = aggr + (size_t)b * NP * DD;
    const short8* w2v = (const short8*)w2f;
    #pragma unroll
    for (int ph = 0; ph < 2; ++ph) {
        float b2r4[4];
        #pragma unroll
        for (int ntl = 0; ntl < 4; ++ntl) b2r4[ntl] = b2[(ph * 4 + ntl) * 16 + l16];

        floatx4 acc[2][4];
        #pragma unroll
        for (int mt = 0; mt < 2; ++mt)
            #pragma unroll
            for (int ntl = 0; ntl < 4; ++ntl)
                #pragma unroll
                for (int r = 0; r < 4; ++r) acc[mt][ntl][r] = b2r4[ntl];

        #pragma unroll
        for (int ks = 0; ks < 4; ++ks) {
            short8 bf[4];
            #pragma unroll
            for (int ntl = 0; ntl < 4; ++ntl)
                bf[ntl] = w2v[(ks * 8 + ph * 4 + ntl) * 64 + lane];
            #pragma unroll
            for (int mt = 0; mt < 2; ++mt) {
                short8 af = __builtin_bit_cast(short8, mid[mt][ks]);
                #pragma unroll
                for (int ntl = 0; ntl < 4; ++ntl)
                    acc[mt][ntl] = __builtin_amdgcn_mfma_f32_16x16x32_bf16(af, bf[ntl], acc[mt][ntl], 0, 0, 0);
            }
        }

        #pragma unroll
        for (int sp = 0; sp < 2; ++sp) {
            #pragma unroll
            for (int mt = 0; mt < 2; ++mt)
                #pragma unroll
                for (int j = 0; j < 2; ++j) {
                    const int ntl = sp * 2 + j;
                    #pragma unroll
                    for (int r = 0; r < 4; ++r)
                        s_red[(ew + mt * 16 + quad * 4 + r) * RSF + j * 16 + l16] =
                            lrelu(acc[mt][ntl][r]);
                }

            const int d = ph * 64 + sp * 32 + colL;
            float* ab = aggr_bd + d;
            float run = 0.0f;
            int cid = cid0;
            #pragma unroll
            for (int r = 0; r < 16; ++r) {
                float v = s_red[(rbase + r) * RSF + colL];
                if (bmask & (1 << r)) {
                    atomicAdd(ab + (size_t)cid * DD, run);
                    run = 0.0f;
                    cid = s_col[rbase + r];
                }
                run += v;
            }
            atomicAdd(ab + (size_t)cid * DD, run);
        }
    }
}

// ---------------- node MLP: R12 col-split GEMM2/PQ + NEW R14 GEMM1 register-pass split ----------------
// GEMM1 restructured: aggr-derived A-fragments (af_agg[4]) hoisted + computed ONCE
// (cwacc + self-clean preserved), then two 64-col passes with acc[4]/bf[4] instead of
// one pass with acc[8]/bf[8]. Peak live regs in the GEMM1 region drop ~32 -> may cross
// the 128-reg occupancy step (3 -> 4 waves/SIMD). w1 total traffic unchanged (each pass
// reads its own column half); A-fragments re-read from LDS (free). Meter: total time.
__global__ __launch_bounds__(256) void k_node(
    ushort* hb, float* aggr, const float* __restrict__ cnt,
    const float* __restrict__ cw, const float* __restrict__ cb,
    const ushort* __restrict__ w1f, const float* __restrict__ b1,
    const ushort* __restrict__ w2f, const float* __restrict__ b2,
    float* __restrict__ pos,
    int do_pq,
    const ushort* __restrict__ wtn, const ushort* __restrict__ wmn,
    const float* __restrict__ b1n,
    ushort* __restrict__ P, ushort* __restrict__ Q)
{
    __shared__ __align__(16) ushort s_mid[64 * MSTR];
    __shared__ __align__(16) ushort s_ho[64 * MSTR];

    const int g    = blockIdx.x;
    const int b    = (g & 7) >> 1;
    const int n0   = ((g >> 3) * 2 + (g & 1)) * 64;
    const int t    = threadIdx.x;
    const int w    = t >> 6, lane = t & 63;
    const int quad = lane >> 4, l16 = lane & 15;
    const int rw   = w * 16;
    const int nw   = n0 + rw;
    const int w2i  = w * 2;

    #pragma unroll
    for (int i = 0; i < 4; ++i) {
        int row = rw + i * 4 + quad;
        short8 v = *(const short8*)(hb + ((size_t)b * NP + n0 + row) * DD + l16 * 8);
        *(short8*)&s_ho[row * MSTR + l16 * 8] = v;
    }

    float* aptr = aggr + ((size_t)b * NP + nw + l16) * DD;
    float inv = 0.0f;
    {
        int node = nw + l16;
        if (node < NN) { float dn = cnt[node]; inv = 1.0f / fmaxf(dn, 1.0f); }
    }
    float b1r[8];
    #pragma unroll
    for (int nt = 0; nt < 8; ++nt) b1r[nt] = b1[nt * 16 + l16];
    float b2r2[2];
    #pragma unroll
    for (int nt = 0; nt < 2; ++nt) b2r2[nt] = b2[(w2i + nt) * 16 + l16];

    // ---- af_agg: aggr-derived A-fragments for ks 4..7, ONCE (cwacc + self-clean) ----
    short8 af_agg[4];
    float cwacc = 0.0f;
    {
        const floatx4 zero4 = {0.0f, 0.0f, 0.0f, 0.0f};
        #pragma unroll
        for (int ka = 0; ka < 4; ++ka) {
            const int koff = ka * 32 + quad * 8;
            floatx4 cw0 = *(const floatx4*)(cw + koff);
            floatx4 cw1 = *(const floatx4*)(cw + koff + 4);
            floatx4 a0 = *(const floatx4*)(aptr + koff);
            floatx4 a1 = *(const floatx4*)(aptr + koff + 4);
            *(floatx4*)(aptr + koff)     = zero4;   // self-clean for next layer
            *(floatx4*)(aptr + koff + 4) = zero4;
            short8 af;
            #pragma unroll
            for (int j = 0; j < 4; ++j) {
                float v = a0[j] * inv;
                af[j] = (short)f2bf(v);
                cwacc += v * cw0[j];
            }
            #pragma unroll
            for (int j = 0; j < 4; ++j) {
                float v = a1[j] * inv;
                af[4 + j] = (short)f2bf(v);
                cwacc += v * cw1[j];
            }
            af_agg[ka] = af;
        }
    }

    // coord update (cwacc complete)
    {
        float full = cwacc;
        full += __shfl_xor(full, 16);
        full += __shfl_xor(full, 32);
        int node = nw + l16;
        if (quad == 0 && node < NN) {
            float cu = 0.1f * tanhf(full + cb[0]);
            float* pp = pos + ((size_t)b * NN + node) * 3;
            pp[0] += cu; pp[1] += cu; pp[2] += cu;
        }
    }

    // ---- GEMM1 in two 64-col passes (acc[4]/bf[4]) ----
    const short8* w1v = (const short8*)w1f;
    #pragma unroll
    for (int p = 0; p < 2; ++p) {
        floatx4 acc[4];
        #pragma unroll
        for (int nt = 0; nt < 4; ++nt)
            #pragma unroll
            for (int r = 0; r < 4; ++r) acc[nt][r] = b1r[p * 4 + nt];

        #pragma unroll
        for (int ks = 0; ks < 8; ++ks) {
            short8 bf[4];
            #pragma unroll
            for (int nt = 0; nt < 4; ++nt)
                bf[nt] = w1v[(ks * 8 + p * 4 + nt) * 64 + lane];
            short8 af;
            if (ks < 4) af = *(const short8*)(&s_ho[(rw + l16) * MSTR + ks * 32 + quad * 8]);
            else        af = af_agg[ks - 4];
            #pragma unroll
            for (int nt = 0; nt < 4; ++nt)
                acc[nt] = __builtin_amdgcn_mfma_f32_16x16x32_bf16(af, bf[nt], acc[nt], 0, 0, 0);
        }

        #pragma unroll
        for (int nt = 0; nt < 4; ++nt)
            #pragma unroll
            for (int r = 0; r < 4; ++r)
                s_mid[(rw + quad * 4 + r) * MSTR + (p * 4 + nt) * 16 + l16] =
                    f2bf(lrelu(acc[nt][r]));
    }

    __syncthreads();   // A: s_mid (mid) + s_ho (old h) block-visible

    // ---- GEMM2 column-split (R12): all 64 rows x cols [w*32, w*32+32) ----
    floatx4 acc2[4][2];
    #pragma unroll
    for (int rt = 0; rt < 4; ++rt)
        #pragma unroll
        for (int nt = 0; nt < 2; ++nt)
            #pragma unroll
            for (int r = 0; r < 4; ++r) acc2[rt][nt][r] = b2r2[nt];

    const short8* w2v = (const short8*)w2f;
    #pragma unroll
    for (int ks = 0; ks < 4; ++ks) {
        short8 bfc[2];
        #pragma unroll
        for (int nt = 0; nt < 2; ++nt)
            bfc[nt] = w2v[(ks * 8 + w2i + nt) * 64 + lane];
        #pragma unroll
        for (int rt = 0; rt < 4; ++rt) {
            short8 af = *(const short8*)(&s_mid[(rt * 16 + l16) * MSTR + ks * 32 + quad * 8]);
            #pragma unroll
            for (int nt = 0; nt < 2; ++nt)
                acc2[rt][nt] = __builtin_amdgcn_mfma_f32_16x16x32_bf16(af, bfc[nt], acc2[rt][nt], 0, 0, 0);
        }
    }

    __syncthreads();   // B: all s_mid reads done before overwrite

    #pragma unroll
    for (int rt = 0; rt < 4; ++rt)
        #pragma unroll
        for (int nt = 0; nt < 2; ++nt)
            #pragma unroll
            for (int r = 0; r < 4; ++r) {
                int row = rt * 16 + quad * 4 + r;
                int col = w2i * 16 + nt * 16 + l16;
                float hold = bf2f(s_ho[row * MSTR + col]);
                s_mid[row * MSTR + col] = f2bf(hold + lrelu(acc2[rt][nt][r]));
            }

    __syncthreads();   // C: new h complete; s_ho dead

    #pragma unroll
    for (int i = 0; i < 4; ++i) {
        int row = rw + i * 4 + quad;
        int n = n0 + row;
        short8 v = *(const short8*)&s_mid[row * MSTR + l16 * 8];
        if (n < NN)
            *(short8*)(hb + ((size_t)b * NP + n) * DD + l16 * 8) = v;
    }

    if (do_pq) {
        const short8* wt = (const short8*)wtn;
        const short8* wm = (const short8*)wmn;
        float b1nr2[2];
        #pragma unroll
        for (int nt = 0; nt < 2; ++nt) b1nr2[nt] = b1n[(w2i + nt) * 16 + l16];

        #pragma unroll
        for (int pass = 0; pass < 2; ++pass) {
            floatx4 ap[4][2];
            #pragma unroll
            for (int rt = 0; rt < 4; ++rt)
                #pragma unroll
                for (int nt = 0; nt < 2; ++nt)
                    #pragma unroll
                    for (int r = 0; r < 4; ++r) ap[rt][nt][r] = pass ? b1nr2[nt] : 0.0f;
            const short8* wv = pass ? wm : wt;
            #pragma unroll
            for (int ks = 0; ks < 4; ++ks) {
                short8 bfp[2];
                #pragma unroll
                for (int nt = 0; nt < 2; ++nt)
                    bfp[nt] = wv[(ks * 8 + w2i + nt) * 64 + lane];
                #pragma unroll
                for (int rt = 0; rt < 4; ++rt) {
                    short8 af = *(const short8*)(&s_mid[(rt * 16 + l16) * MSTR + ks * 32 + quad * 8]);
                    #pragma unroll
                    for (int nt = 0; nt < 2; ++nt)
                        ap[rt][nt] = __builtin_amdgcn_mfma_f32_16x16x32_bf16(af, bfp[nt], ap[rt][nt], 0, 0, 0);
                }
            }
            if (pass) __syncthreads();
            #pragma unroll
            for (int rt = 0; rt < 4; ++rt)
                #pragma unroll
                for (int nt = 0; nt < 2; ++nt)
                    #pragma unroll
                    for (int r = 0; r < 4; ++r)
                        s_ho[(rt * 16 + quad * 4 + r) * MSTR + w2i * 16 + nt * 16 + l16] =
                            f2bf(ap[rt][nt][r]);
            __syncthreads();
            ushort* dst = pass ? Q : P;
            #pragma unroll
            for (int i = 0; i < 4; ++i) {
                int row = rw + i * 4 + quad;
                short8 v = *(const short8*)&s_ho[row * MSTR + l16 * 8];
                *(short8*)(dst + ((size_t)b * NP + n0 + row) * DD + l16 * 8) = v;
            }
        }
    }
}

#define NPC 50
__global__ void k_mean(const ushort* __restrict__ hb, float* __restrict__ hm) {
    int b  = blockIdx.y;
    int n0 = blockIdx.x * NPC;
    int d  = threadIdx.x;
    float s = 0.0f;
    for (int n = n0; n < n0 + NPC; ++n) s += bf2f(hb[((size_t)b * NP + n) * DD + d]);
    atomicAdd(&hm[b * DD + d], s);
}

__global__ void k_proj(const float* __restrict__ hm, const float* __restrict__ wp,
                       const float* __restrict__ bp, float* __restrict__ out) {
    int t = threadIdx.x;
    int b = t >> 6, o = t & (OUTD - 1);
    float s = 0.0f;
    for (int d2 = 0; d2 < DD; ++d2) s += hm[b * DD + d2] * wp[d2 * OUTD + o];
    s = s * (1.0f / NN) + bp[o];
    out[b * OUTD + o] = lrelu(s);
}

extern "C" void kernel_launch(void* const* d_in, const int* in_sizes, int n_in,
                              void* d_out, int out_size, void* d_ws, size_t ws_size,
                              hipStream_t stream) {
    (void)in_sizes; (void)n_in; (void)out_size; (void)ws_size;
    const float* x   = (const float*)d_in[0];
    const int*   ei  = (const int*)d_in[1];
    const float* w0  = (const float*)d_in[2];
    const float* b0  = (const float*)d_in[3];
    const float* ew1 = (const float*)d_in[4];
    const float* eb1 = (const float*)d_in[5];
    const float* ew2 = (const float*)d_in[6];
    const float* eb2 = (const float*)d_in[7];
    const float* cw  = (const float*)d_in[8];
    const float* cb  = (const float*)d_in[9];
    const float* nw1 = (const float*)d_in[10];
    const float* nb1 = (const float*)d_in[11];
    const float* nw2 = (const float*)d_in[12];
    const float* nb2 = (const float*)d_in[13];
    const float* wp  = (const float*)d_in[14];
    const float* bp  = (const float*)d_in[15];
    const int* row = ei;
    const int* col = ei + EE;

    const size_t HSZ = (size_t)BB * NP * DD;
    float* ws   = (float*)d_ws;
    float* aggr = ws;
    float* pos  = aggr + HSZ;
    float* cnt  = pos + (size_t)BB * NN * 3;
    float* hm   = cnt + NN;
    ushort* hb    = (ushort*)(hm + 512);
    ushort* Pb    = hb + HSZ;
    ushort* Qb    = Pb + HSZ;
    ushort* wtopf = Qb + HSZ;                           // LL*16384
    ushort* wmidf = wtopf + (size_t)LL * 16384;
    ushort* ew2f  = wmidf + (size_t)LL * 16384;
    ushort* nw1f  = ew2f + (size_t)LL * 16384;          // LL*32768
    ushort* nw2f  = nw1f + (size_t)LL * 32768;
    int* ecnt   = (int*)(nw2f + (size_t)LL * 16384);
    int* cursor = ecnt + NN;
    int* rowS   = cursor + NN;
    int* colS   = rowS + EE;

    hipMemcpyAsync(pos, x, sizeof(float) * (size_t)BB * NN * 3,
                   hipMemcpyDeviceToDevice, stream);
    hipMemsetAsync(cnt, 0, sizeof(float) * NN, stream);
    hipMemsetAsync(ecnt, 0, sizeof(int) * NN, stream);
    hipMemsetAsync(hm, 0, sizeof(float) * BB * DD, stream);
    hipMemsetAsync(aggr, 0, sizeof(float) * HSZ, stream);   // layers 1..3 self-cleaned by k_node

    k_cvtw_all<<<192, 256, 0, stream>>>(ew1, ew2, nw1, nw2,
                                        wtopf, wmidf, ew2f, nw1f, nw2f);

    k_h0<<<((int)HSZ + 255) / 256, 256, 0, stream>>>(x, w0, b0, hb);
    k_count<<<(EE + 255) / 256, 256, 0, stream>>>(col, cnt, ecnt);
    k_scan<<<1, 256, 0, stream>>>(ecnt, cursor);
    k_place<<<(EE + 255) / 256, 256, 0, stream>>>(row, col, cursor, rowS, colS);

    k_pq<<<(NP / 64) * BB, 256, 0, stream>>>(hb, wtopf, wmidf, eb1, Pb, Qb);

    for (int i = 0; i < LL; ++i) {
        k_edge<<<(EE / 128) * BB, 256, 0, stream>>>(
            pos, Pb, Qb, rowS, colS,
            ew1 + (size_t)i * 257 * DD + (size_t)256 * DD,
            ew2f + (size_t)i * 16384,
            eb2 + (size_t)i * DD,
            aggr);
        int nx = (i < LL - 1) ? (i + 1) : i;
        k_node<<<(NP / 64) * BB, 256, 0, stream>>>(
            hb, aggr, cnt,
            cw + (size_t)i * DD, cb + i,
            nw1f + (size_t)i * 32768, nb1 + (size_t)i * DD,
            nw2f + (size_t)i * 16384, nb2 + (size_t)i * DD,
            pos,
            (i < LL - 1) ? 1 : 0,
            wtopf + (size_t)nx * 16384, wmidf + (size_t)nx * 16384,
            eb1 + (size_t)nx * DD,
            Pb, Qb);
    }

    k_mean<<<dim3(NN / NPC, BB), DD, 0, stream>>>(hb, hm);
    k_proj<<<1, 256, 0, stream>>>(hm, wp, bp, (float*)d_out);
}

// Round 15
// 560.209 us; speedup vs baseline: 1.3586x; 1.0033x over previous
//
#include <hip/hip_runtime.h>
#include <hip/hip_bf16.h>
#include <math.h>

#define BB   4
#define NN   10000
#define NP   10112          // NN padded to multiple of 128
#define EE   160000         // = 1250 * 128
#define DD   128
#define OUTD 64
#define LL   4
#define NEGS 0.01f
#define MSTR 136            // s_mid/s_ho row stride (bf16 elems), 272B/row
#define RSF  34             // s_red row stride (fp32): 2-way max on read+write (~free)

typedef __attribute__((ext_vector_type(8))) short   short8;
typedef __attribute__((ext_vector_type(4))) float   floatx4;
typedef __attribute__((ext_vector_type(4))) uint    uintx4;

__device__ __forceinline__ float lrelu(float x) { return fmaxf(x, NEGS * x); }
__device__ __forceinline__ ushort f2bf(float x) {
    uint u = __builtin_bit_cast(uint, x);
    return (ushort)((u + 0x7FFFu + ((u >> 16) & 1u)) >> 16);
}
__device__ __forceinline__ float bf2f(ushort u) {
    uint v = ((uint)u) << 16;
    return __builtin_bit_cast(float, v);
}
__device__ __forceinline__ float bcf(uint u) { return __builtin_bit_cast(float, u); }

// ---- all weights -> MFMA B-fragment layout in ONE launch (192 blocks x 256)
__global__ void k_cvtw_all(const float* __restrict__ ew1, const float* __restrict__ ew2,
                           const float* __restrict__ nw1, const float* __restrict__ nw2,
                           ushort* __restrict__ wtopf, ushort* __restrict__ wmidf,
                           ushort* __restrict__ ew2f, ushort* __restrict__ nw1f,
                           ushort* __restrict__ nw2f) {
    int tid = blockIdx.x * 256 + threadIdx.x;
    const float* src; ushort* dst; int pitch, nks, loc;
    if (tid < 8192)       { src = ew1;                     dst = wtopf; pitch = 257; nks = 4; loc = tid; }
    else if (tid < 16384) { src = ew1 + (size_t)128 * DD;  dst = wmidf; pitch = 257; nks = 4; loc = tid - 8192; }
    else if (tid < 24576) { src = ew2;                     dst = ew2f;  pitch = 128; nks = 4; loc = tid - 16384; }
    else if (tid < 40960) { src = nw1;                     dst = nw1f;  pitch = 256; nks = 8; loc = tid - 24576; }
    else                  { src = nw2;                     dst = nw2f;  pitch = 128; nks = 4; loc = tid - 40960; }
    int lane = loc & 63;
    int nt   = (loc >> 6) & 7;
    int ks   = (loc >> 9) % nks;
    int l    = loc / (nks * 512);
    int quad = lane >> 4, l16 = lane & 15;
    int n = nt * 16 + l16;
    const float* s = src + (size_t)l * pitch * DD;
    ushort* d = dst + (size_t)loc * 8;
    #pragma unroll
    for (int j = 0; j < 8; ++j)
        d[j] = f2bf(s[(size_t)(ks * 32 + quad * 8 + j) * DD + n]);
}

// h0: bf16 only (no fp32 master)
__global__ void k_h0(const float* __restrict__ x, const float* __restrict__ w0,
                     const float* __restrict__ b0, ushort* __restrict__ hb) {
    int idx = blockIdx.x * 256 + threadIdx.x;
    if (idx >= BB * NP * DD) return;
    int d  = idx & (DD - 1);
    int bn = idx >> 7;
    int n  = bn % NP, b = bn / NP;
    float v = 0.0f;
    if (n < NN) {
        const float* p = x + ((size_t)b * NN + n) * 3;
        v = lrelu(b0[d] + p[0] * w0[d] + p[1] * w0[DD + d] + p[2] * w0[2 * DD + d]);
    }
    hb[idx] = f2bf(v);
}

__global__ void k_count(const int* __restrict__ col, float* __restrict__ cnt,
                        int* __restrict__ ecnt) {
    int e = blockIdx.x * blockDim.x + threadIdx.x;
    if (e < EE) {
        int c = col[e];
        atomicAdd(&cnt[c], 1.0f);
        atomicAdd(&ecnt[c], 1);
    }
}

// parallel Hillis-Steele scan (was: thread-0 serial 256-walk, ~3us)
__global__ __launch_bounds__(256) void k_scan(const int* __restrict__ ecnt,
                                              int* __restrict__ cursor) {
    __shared__ int s_sum[256];
    int t = threadIdx.x;
    int base = t * 40;
    int own = 0;
    for (int i = 0; i < 40; ++i) {
        int n = base + i;
        if (n < NN) own += ecnt[n];
    }
    s_sum[t] = own;
    __syncthreads();
    #pragma unroll
    for (int off = 1; off < 256; off <<= 1) {
        int u = (t >= off) ? s_sum[t - off] : 0;
        __syncthreads();
        if (t >= off) s_sum[t] += u;
        __syncthreads();
    }
    int a = s_sum[t] - own;   // exclusive prefix
    for (int i = 0; i < 40; ++i) {
        int n = base + i;
        if (n < NN) { cursor[n] = a; a += ecnt[n]; }
    }
}

__global__ void k_place(const int* __restrict__ row, const int* __restrict__ col,
                        int* __restrict__ cursor,
                        int* __restrict__ rowS, int* __restrict__ colS) {
    int e = blockIdx.x * blockDim.x + threadIdx.x;
    if (e >= EE) return;
    int c = col[e];
    int p = atomicAdd(&cursor[c], 1);
    rowS[p] = row[e];
    colS[p] = c;
}

// ---------------- initial P/Q (layer 0), 64-node blocks ----------------
__global__ __launch_bounds__(256) void k_pq(
    const ushort* __restrict__ hb, const ushort* __restrict__ wtf,
    const ushort* __restrict__ wmf, const float* __restrict__ b1,
    ushort* __restrict__ P, ushort* __restrict__ Q)
{
    __shared__ __align__(16) ushort s_out[64 * MSTR];
    const int g = blockIdx.x;
    const int b = (g & 7) >> 1;
    const int n0 = ((g >> 3) * 2 + (g & 1)) * 64;
    const int t = threadIdx.x;
    const int w = t >> 6, lane = t & 63, quad = lane >> 4, l16 = lane & 15;
    const int rw = w * 16;
    const int nw = n0 + rw;

    const ushort* hptr = hb + ((size_t)b * NP + nw + l16) * DD;
    float b1r[8];
    #pragma unroll
    for (int nt = 0; nt < 8; ++nt) b1r[nt] = b1[nt * 16 + l16];

    const short8* wt = (const short8*)wtf;
    const short8* wm = (const short8*)wmf;

    #pragma unroll
    for (int pass = 0; pass < 2; ++pass) {
        floatx4 ap[8];
        #pragma unroll
        for (int nt = 0; nt < 8; ++nt)
            #pragma unroll
            for (int r = 0; r < 4; ++r) ap[nt][r] = pass ? b1r[nt] : 0.0f;
        const short8* wv = pass ? wm : wt;
        #pragma unroll
        for (int ks = 0; ks < 4; ++ks) {
            short8 bf[8];
            #pragma unroll
            for (int nt = 0; nt < 8; ++nt) bf[nt] = wv[(ks * 8 + nt) * 64 + lane];
            short8 af = *(const short8*)(hptr + ks * 32 + quad * 8);
            #pragma unroll
            for (int nt = 0; nt < 8; ++nt)
                ap[nt] = __builtin_amdgcn_mfma_f32_16x16x32_bf16(af, bf[nt], ap[nt], 0, 0, 0);
        }
        #pragma unroll
        for (int nt = 0; nt < 8; ++nt)
            #pragma unroll
            for (int r = 0; r < 4; ++r)
                s_out[(rw + quad * 4 + r) * MSTR + nt * 16 + l16] = f2bf(ap[nt][r]);
        ushort* dst = pass ? Q : P;
        #pragma unroll
        for (int i = 0; i < 4; ++i) {
            int row = rw + i * 4 + quad;
            short8 v = *(const short8*)&s_out[row * MSTR + l16 * 8];
            *(short8*)(dst + ((size_t)b * NP + n0 + row) * DD + l16 * 8) = v;
        }
    }
}

// ---------------- edge kernel: R4/R9 fused body (structural floor ~75us) ----------------
// 8 falsified theories incl. R13 phase-split (k_gemm alone = 72us proves back-end is
// the floor; gathers fully hidden). Accepted.
__global__ __launch_bounds__(256, 4) void k_edge(
    const float* __restrict__ pos,
    const ushort* __restrict__ P, const ushort* __restrict__ Q,
    const int* __restrict__ rowS, const int* __restrict__ colS,
    const float* __restrict__ w1last,
    const ushort* __restrict__ w2f, const float* __restrict__ b2,
    float* __restrict__ aggr)
{
    __shared__ __align__(16) int    s_col[128];
    __shared__ __align__(16) float  s_ds[128];
    __shared__ __align__(16) float  s_red[128 * RSF];

    const int g    = blockIdx.x;
    const int b    = (g & 7) >> 1;
    const int tile = (g >> 3) * 2 + (g & 1);
    const int e0   = tile * 128;
    const int t    = threadIdx.x;
    const int w    = t >> 6, lane = t & 63;
    const int quad = lane >> 4, l16 = lane & 15;
    const int ew   = w * 32;

    const ushort* pp[2];
    const ushort* qp[2];
    #pragma unroll
    for (int mt = 0; mt < 2; ++mt) {
        int el = e0 + ew + mt * 16 + l16;
        pp[mt] = P + ((size_t)b * NP + rowS[el]) * DD;
        qp[mt] = Q + ((size_t)b * NP + colS[el]) * DD;
    }

    uintx4 pf[2][4], qf[2][4];
    #pragma unroll
    for (int ks = 0; ks < 4; ++ks) {
        const int koff = ks * 32 + quad * 8;
        #pragma unroll
        for (int mt = 0; mt < 2; ++mt) {
            pf[mt][ks] = *(const uintx4*)(pp[mt] + koff);
            qf[mt][ks] = *(const uintx4*)(qp[mt] + koff);
        }
    }

    if (t < 128) {
        int e = e0 + t;
        int r = rowS[e], c = colS[e];
        s_col[t] = c;
        const float* pr = pos + ((size_t)b * NN + r) * 3;
        const float* pc = pos + ((size_t)b * NN + c) * 3;
        float dx = pr[0] - pc[0], dy = pr[1] - pc[1], dz = pr[2] - pc[2];
        s_ds[t] = dx * dx + dy * dy + dz * dz;
    }
    __syncthreads();

    const int rh    = lane >> 5;
    const int colL  = lane & 31;
    const int rbase = ew + rh * 16;
    int bmask = 0, cid0;
    {
        int prev = s_col[rbase];
        cid0 = prev;
        #pragma unroll
        for (int r2 = 1; r2 < 16; ++r2) {
            int c = s_col[rbase + r2];
            if (c != prev) bmask |= (1 << r2);
            prev = c;
        }
    }

    float dsv[2];
    #pragma unroll
    for (int mt = 0; mt < 2; ++mt) dsv[mt] = s_ds[ew + mt * 16 + l16];

    uintx4 mid[2][4];
    #pragma unroll
    for (int ks = 0; ks < 4; ++ks) {
        const int koff = ks * 32 + quad * 8;
        floatx4 wl0 = *(const floatx4*)(w1last + koff);
        floatx4 wl1 = *(const floatx4*)(w1last + koff + 4);
        float wl[8] = {wl0[0], wl0[1], wl0[2], wl0[3], wl1[0], wl1[1], wl1[2], wl1[3]};
        #pragma unroll
        for (int mt = 0; mt < 2; ++mt) {
            #pragma unroll
            for (int i = 0; i < 4; ++i) {
                uint pv = pf[mt][ks][i], qv = qf[mt][ks][i];
                float vlo = lrelu(bcf(pv << 16) + bcf(qv << 16) + dsv[mt] * wl[2 * i]);
                float vhi = lrelu(bcf(pv & 0xFFFF0000u) + bcf(qv & 0xFFFF0000u) + dsv[mt] * wl[2 * i + 1]);
                mid[mt][ks][i] = __builtin_amdgcn_perm(
                    __builtin_bit_cast(uint, vhi), __builtin_bit_cast(uint, vlo), 0x07060302u);
            }
        }
    }

    float* aggr_bd = aggr + (size_t)b * NP * DD;
    const short8* w2v = (const short8*)w2f;
    #pragma unroll
    for (int ph = 0; ph < 2; ++ph) {
        float b2r4[4];
        #pragma unroll
        for (int ntl = 0; ntl < 4; ++ntl) b2r4[ntl] = b2[(ph * 4 + ntl) * 16 + l16];

        floatx4 acc[2][4];
        #pragma unroll
        for (int mt = 0; mt < 2; ++mt)
            #pragma unroll
            for (int ntl = 0; ntl < 4; ++ntl)
                #pragma unroll
                for (int r = 0; r < 4; ++r) acc[mt][ntl][r] = b2r4[ntl];

        #pragma unroll
        for (int ks = 0; ks < 4; ++ks) {
            short8 bf[4];
            #pragma unroll
            for (int ntl = 0; ntl < 4; ++ntl)
                bf[ntl] = w2v[(ks * 8 + ph * 4 + ntl) * 64 + lane];
            #pragma unroll
            for (int mt = 0; mt < 2; ++mt) {
                short8 af = __builtin_bit_cast(short8, mid[mt][ks]);
                #pragma unroll
                for (int ntl = 0; ntl < 4; ++ntl)
                    acc[mt][ntl] = __builtin_amdgcn_mfma_f32_16x16x32_bf16(af, bf[ntl], acc[mt][ntl], 0, 0, 0);
            }
        }

        #pragma unroll
        for (int sp = 0; sp < 2; ++sp) {
            #pragma unroll
            for (int mt = 0; mt < 2; ++mt)
                #pragma unroll
                for (int j = 0; j < 2; ++j) {
                    const int ntl = sp * 2 + j;
                    #pragma unroll
                    for (int r = 0; r < 4; ++r)
                        s_red[(ew + mt * 16 + quad * 4 + r) * RSF + j * 16 + l16] =
                            lrelu(acc[mt][ntl][r]);
                }

            const int d = ph * 64 + sp * 32 + colL;
            float* ab = aggr_bd + d;
            float run = 0.0f;
            int cid = cid0;
            #pragma unroll
            for (int r = 0; r < 16; ++r) {
                float v = s_red[(rbase + r) * RSF + colL];
                if (bmask & (1 << r)) {
                    atomicAdd(ab + (size_t)cid * DD, run);
                    run = 0.0f;
                    cid = s_col[rbase + r];
                }
                run += v;
            }
            atomicAdd(ab + (size_t)cid * DD, run);
        }
    }
}

// ---------------- node MLP: R14 reg-pass-split GEMM1 + R12 col-split GEMM2/PQ
// + R15 fused mean (do_pq==0): last layer sums its 64 new-h rows from LDS and
// atomicAdds per (b,d) -- deletes the k_mean dispatch and its 10.4MB hb re-read.
__global__ __launch_bounds__(256) void k_node(
    ushort* hb, float* aggr, const float* __restrict__ cnt,
    const float* __restrict__ cw, const float* __restrict__ cb,
    const ushort* __restrict__ w1f, const float* __restrict__ b1,
    const ushort* __restrict__ w2f, const float* __restrict__ b2,
    float* __restrict__ pos,
    int do_pq,
    const ushort* __restrict__ wtn, const ushort* __restrict__ wmn,
    const float* __restrict__ b1n,
    ushort* __restrict__ P, ushort* __restrict__ Q,
    float* __restrict__ hm)
{
    __shared__ __align__(16) ushort s_mid[64 * MSTR];
    __shared__ __align__(16) ushort s_ho[64 * MSTR];

    const int g    = blockIdx.x;
    const int b    = (g & 7) >> 1;
    const int n0   = ((g >> 3) * 2 + (g & 1)) * 64;
    const int t    = threadIdx.x;
    const int w    = t >> 6, lane = t & 63;
    const int quad = lane >> 4, l16 = lane & 15;
    const int rw   = w * 16;
    const int nw   = n0 + rw;
    const int w2i  = w * 2;

    #pragma unroll
    for (int i = 0; i < 4; ++i) {
        int row = rw + i * 4 + quad;
        short8 v = *(const short8*)(hb + ((size_t)b * NP + n0 + row) * DD + l16 * 8);
        *(short8*)&s_ho[row * MSTR + l16 * 8] = v;
    }

    float* aptr = aggr + ((size_t)b * NP + nw + l16) * DD;
    float inv = 0.0f;
    {
        int node = nw + l16;
        if (node < NN) { float dn = cnt[node]; inv = 1.0f / fmaxf(dn, 1.0f); }
    }
    float b1r[8];
    #pragma unroll
    for (int nt = 0; nt < 8; ++nt) b1r[nt] = b1[nt * 16 + l16];
    float b2r2[2];
    #pragma unroll
    for (int nt = 0; nt < 2; ++nt) b2r2[nt] = b2[(w2i + nt) * 16 + l16];

    // af_agg: aggr-derived A-fragments for ks 4..7, ONCE (cwacc + self-clean)
    short8 af_agg[4];
    float cwacc = 0.0f;
    {
        const floatx4 zero4 = {0.0f, 0.0f, 0.0f, 0.0f};
        #pragma unroll
        for (int ka = 0; ka < 4; ++ka) {
            const int koff = ka * 32 + quad * 8;
            floatx4 cw0 = *(const floatx4*)(cw + koff);
            floatx4 cw1 = *(const floatx4*)(cw + koff + 4);
            floatx4 a0 = *(const floatx4*)(aptr + koff);
            floatx4 a1 = *(const floatx4*)(aptr + koff + 4);
            *(floatx4*)(aptr + koff)     = zero4;   // self-clean for next layer
            *(floatx4*)(aptr + koff + 4) = zero4;
            short8 af;
            #pragma unroll
            for (int j = 0; j < 4; ++j) {
                float v = a0[j] * inv;
                af[j] = (short)f2bf(v);
                cwacc += v * cw0[j];
            }
            #pragma unroll
            for (int j = 0; j < 4; ++j) {
                float v = a1[j] * inv;
                af[4 + j] = (short)f2bf(v);
                cwacc += v * cw1[j];
            }
            af_agg[ka] = af;
        }
    }

    // coord update (cwacc complete)
    {
        float full = cwacc;
        full += __shfl_xor(full, 16);
        full += __shfl_xor(full, 32);
        int node = nw + l16;
        if (quad == 0 && node < NN) {
            float cu = 0.1f * tanhf(full + cb[0]);
            float* pp = pos + ((size_t)b * NN + node) * 3;
            pp[0] += cu; pp[1] += cu; pp[2] += cu;
        }
    }

    // GEMM1 in two 64-col passes (acc[4]/bf[4])
    const short8* w1v = (const short8*)w1f;
    #pragma unroll
    for (int p = 0; p < 2; ++p) {
        floatx4 acc[4];
        #pragma unroll
        for (int nt = 0; nt < 4; ++nt)
            #pragma unroll
            for (int r = 0; r < 4; ++r) acc[nt][r] = b1r[p * 4 + nt];

        #pragma unroll
        for (int ks = 0; ks < 8; ++ks) {
            short8 bf[4];
            #pragma unroll
            for (int nt = 0; nt < 4; ++nt)
                bf[nt] = w1v[(ks * 8 + p * 4 + nt) * 64 + lane];
            short8 af;
            if (ks < 4) af = *(const short8*)(&s_ho[(rw + l16) * MSTR + ks * 32 + quad * 8]);
            else        af = af_agg[ks - 4];
            #pragma unroll
            for (int nt = 0; nt < 4; ++nt)
                acc[nt] = __builtin_amdgcn_mfma_f32_16x16x32_bf16(af, bf[nt], acc[nt], 0, 0, 0);
        }

        #pragma unroll
        for (int nt = 0; nt < 4; ++nt)
            #pragma unroll
            for (int r = 0; r < 4; ++r)
                s_mid[(rw + quad * 4 + r) * MSTR + (p * 4 + nt) * 16 + l16] =
                    f2bf(lrelu(acc[nt][r]));
    }

    __syncthreads();   // A: s_mid (mid) + s_ho (old h) block-visible

    // GEMM2 column-split: all 64 rows x cols [w*32, w*32+32)
    floatx4 acc2[4][2];
    #pragma unroll
    for (int rt = 0; rt < 4; ++rt)
        #pragma unroll
        for (int nt = 0; nt < 2; ++nt)
            #pragma unroll
            for (int r = 0; r < 4; ++r) acc2[rt][nt][r] = b2r2[nt];

    const short8* w2v = (const short8*)w2f;
    #pragma unroll
    for (int ks = 0; ks < 4; ++ks) {
        short8 bfc[2];
        #pragma unroll
        for (int nt = 0; nt < 2; ++nt)
            bfc[nt] = w2v[(ks * 8 + w2i + nt) * 64 + lane];
        #pragma unroll
        for (int rt = 0; rt < 4; ++rt) {
            short8 af = *(const short8*)(&s_mid[(rt * 16 + l16) * MSTR + ks * 32 + quad * 8]);
            #pragma unroll
            for (int nt = 0; nt < 2; ++nt)
                acc2[rt][nt] = __builtin_amdgcn_mfma_f32_16x16x32_bf16(af, bfc[nt], acc2[rt][nt], 0, 0, 0);
        }
    }

    __syncthreads();   // B: all s_mid reads done before overwrite

    #pragma unroll
    for (int rt = 0; rt < 4; ++rt)
        #pragma unroll
        for (int nt = 0; nt < 2; ++nt)
            #pragma unroll
            for (int r = 0; r < 4; ++r) {
                int row = rt * 16 + quad * 4 + r;
                int col = w2i * 16 + nt * 16 + l16;
                float hold = bf2f(s_ho[row * MSTR + col]);
                s_mid[row * MSTR + col] = f2bf(hold + lrelu(acc2[rt][nt][r]));
            }

    __syncthreads();   // C: new h complete; s_ho dead

    #pragma unroll
    for (int i = 0; i < 4; ++i) {
        int row = rw + i * 4 + quad;
        int n = n0 + row;
        short8 v = *(const short8*)&s_mid[row * MSTR + l16 * 8];
        if (n < NN)
            *(short8*)(hb + ((size_t)b * NP + n) * DD + l16 * 8) = v;
    }

    if (do_pq) {
        const short8* wt = (const short8*)wtn;
        const short8* wm = (const short8*)wmn;
        float b1nr2[2];
        #pragma unroll
        for (int nt = 0; nt < 2; ++nt) b1nr2[nt] = b1n[(w2i + nt) * 16 + l16];

        #pragma unroll
        for (int pass = 0; pass < 2; ++pass) {
            floatx4 ap[4][2];
            #pragma unroll
            for (int rt = 0; rt < 4; ++rt)
                #pragma unroll
                for (int nt = 0; nt < 2; ++nt)
                    #pragma unroll
                    for (int r = 0; r < 4; ++r) ap[rt][nt][r] = pass ? b1nr2[nt] : 0.0f;
            const short8* wv = pass ? wm : wt;
            #pragma unroll
            for (int ks = 0; ks < 4; ++ks) {
                short8 bfp[2];
                #pragma unroll
                for (int nt = 0; nt < 2; ++nt)
                    bfp[nt] = wv[(ks * 8 + w2i + nt) * 64 + lane];
                #pragma unroll
                for (int rt = 0; rt < 4; ++rt) {
                    short8 af = *(const short8*)(&s_mid[(rt * 16 + l16) * MSTR + ks * 32 + quad * 8]);
                    #pragma unroll
                    for (int nt = 0; nt < 2; ++nt)
                        ap[rt][nt] = __builtin_amdgcn_mfma_f32_16x16x32_bf16(af, bfp[nt], ap[rt][nt], 0, 0, 0);
                }
            }
            if (pass) __syncthreads();
            #pragma unroll
            for (int rt = 0; rt < 4; ++rt)
                #pragma unroll
                for (int nt = 0; nt < 2; ++nt)
                    #pragma unroll
                    for (int r = 0; r < 4; ++r)
                        s_ho[(rt * 16 + quad * 4 + r) * MSTR + w2i * 16 + nt * 16 + l16] =
                            f2bf(ap[rt][nt][r]);
            __syncthreads();
            ushort* dst = pass ? Q : P;
            #pragma unroll
            for (int i = 0; i < 4; ++i) {
                int row = rw + i * 4 + quad;
                short8 v = *(const short8*)&s_ho[row * MSTR + l16 * 8];
                *(short8*)(dst + ((size_t)b * NP + n0 + row) * DD + l16 * 8) = v;
            }
        }
    } else {
        // fused mean (last layer): sum valid new-h rows from s_mid into hm[b][d]
        if (t < DD) {
            int rmax = NN - n0;
            if (rmax > 64) rmax = 64;
            if (rmax > 0) {
                float s = 0.0f;
                for (int row = 0; row < rmax; ++row)
                    s += bf2f(s_mid[row * MSTR + t]);
                atomicAdd(&hm[b * DD + t], s);
            }
        }
    }
}

__global__ void k_proj(const float* __restrict__ hm, const float* __restrict__ wp,
                       const float* __restrict__ bp, float* __restrict__ out) {
    int t = threadIdx.x;
    int b = t >> 6, o = t & (OUTD - 1);
    float s = 0.0f;
    for (int d2 = 0; d2 < DD; ++d2) s += hm[b * DD + d2] * wp[d2 * OUTD + o];
    s = s * (1.0f / NN) + bp[o];
    out[b * OUTD + o] = lrelu(s);
}

extern "C" void kernel_launch(void* const* d_in, const int* in_sizes, int n_in,
                              void* d_out, int out_size, void* d_ws, size_t ws_size,
                              hipStream_t stream) {
    (void)in_sizes; (void)n_in; (void)out_size; (void)ws_size;
    const float* x   = (const float*)d_in[0];
    const int*   ei  = (const int*)d_in[1];
    const float* w0  = (const float*)d_in[2];
    const float* b0  = (const float*)d_in[3];
    const float* ew1 = (const float*)d_in[4];
    const float* eb1 = (const float*)d_in[5];
    const float* ew2 = (const float*)d_in[6];
    const float* eb2 = (const float*)d_in[7];
    const float* cw  = (const float*)d_in[8];
    const float* cb  = (const float*)d_in[9];
    const float* nw1 = (const float*)d_in[10];
    const float* nb1 = (const float*)d_in[11];
    const float* nw2 = (const float*)d_in[12];
    const float* nb2 = (const float*)d_in[13];
    const float* wp  = (const float*)d_in[14];
    const float* bp  = (const float*)d_in[15];
    const int* row = ei;
    const int* col = ei + EE;

    const size_t HSZ = (size_t)BB * NP * DD;
    float* ws   = (float*)d_ws;
    float* aggr = ws;
    float* pos  = aggr + HSZ;
    float* cnt  = pos + (size_t)BB * NN * 3;
    float* hm   = cnt + NN;
    ushort* hb    = (ushort*)(hm + 512);
    ushort* Pb    = hb + HSZ;
    ushort* Qb    = Pb + HSZ;
    ushort* wtopf = Qb + HSZ;                           // LL*16384
    ushort* wmidf = wtopf + (size_t)LL * 16384;
    ushort* ew2f  = wmidf + (size_t)LL * 16384;
    ushort* nw1f  = ew2f + (size_t)LL * 16384;          // LL*32768
    ushort* nw2f  = nw1f + (size_t)LL * 32768;
    int* ecnt   = (int*)(nw2f + (size_t)LL * 16384);
    int* cursor = ecnt + NN;
    int* rowS   = cursor + NN;
    int* colS   = rowS + EE;

    hipMemcpyAsync(pos, x, sizeof(float) * (size_t)BB * NN * 3,
                   hipMemcpyDeviceToDevice, stream);
    hipMemsetAsync(cnt, 0, sizeof(float) * NN, stream);
    hipMemsetAsync(ecnt, 0, sizeof(int) * NN, stream);
    hipMemsetAsync(hm, 0, sizeof(float) * BB * DD, stream);
    hipMemsetAsync(aggr, 0, sizeof(float) * HSZ, stream);   // layers 1..3 self-cleaned by k_node

    k_cvtw_all<<<192, 256, 0, stream>>>(ew1, ew2, nw1, nw2,
                                        wtopf, wmidf, ew2f, nw1f, nw2f);

    k_h0<<<((int)HSZ + 255) / 256, 256, 0, stream>>>(x, w0, b0, hb);
    k_count<<<(EE + 255) / 256, 256, 0, stream>>>(col, cnt, ecnt);
    k_scan<<<1, 256, 0, stream>>>(ecnt, cursor);
    k_place<<<(EE + 255) / 256, 256, 0, stream>>>(row, col, cursor, rowS, colS);

    k_pq<<<(NP / 64) * BB, 256, 0, stream>>>(hb, wtopf, wmidf, eb1, Pb, Qb);

    for (int i = 0; i < LL; ++i) {
        k_edge<<<(EE / 128) * BB, 256, 0, stream>>>(
            pos, Pb, Qb, rowS, colS,
            ew1 + (size_t)i * 257 * DD + (size_t)256 * DD,
            ew2f + (size_t)i * 16384,
            eb2 + (size_t)i * DD,
            aggr);
        int nx = (i < LL - 1) ? (i + 1) : i;
        k_node<<<(NP / 64) * BB, 256, 0, stream>>>(
            hb, aggr, cnt,
            cw + (size_t)i * DD, cb + i,
            nw1f + (size_t)i * 32768, nb1 + (size_t)i * DD,
            nw2f + (size_t)i * 16384, nb2 + (size_t)i * DD,
            pos,
            (i < LL - 1) ? 1 : 0,
            wtopf + (size_t)nx * 16384, wmidf + (size_t)nx * 16384,
            eb1 + (size_t)nx * DD,
            Pb, Qb,
            hm);
    }

    k_proj<<<1, 256, 0, stream>>>(hm, wp, bp, (float*)d_out);
}